// Round 11
// baseline (509.346 us; speedup 1.0000x reference)
//
#include <hip/hip_runtime.h>
#include <stdint.h>

// ---------------- problem constants ----------------
#define N_ROWS 4096      // bs*seq = 8*512
#define DDIM   512
#define KCODES 8192
#define NK     (N_ROWS * KCODES)   // 33,554,432
#define HALF_NK 16777216u
#define BS_F   8.0f
#define INV_N  (1.0f / 4096.0f)

// ---------------- ws layout (float offsets) ----------------
// logit region (NK floats):
//  - after k_fused, row n's bf16 encodings live in the FIRST 16KB of row n's
//    32KB slot; the UPPER 16KB halves of slots 0..2047 hold the colsum
//    partials of k_fused block b (slots 2b, 2b+1).
// cbl (8MB) is DEAD after k_gemm1 -> reused as outA (gemm2 k-split partial 0).
#define OFF_LOGIT   0
#define OFF_CNORM   (NK)
#define OFF_ACC     (OFF_CNORM + KCODES)   // [0]=sum p*logp [1]=sum(z-zhat)^2 [2]=entropy [3]=ticket
#define OFF_ZH      (OFF_ACC + 4)                    // bf16 z hi  [4096*512]
#define OFF_ZL      (OFF_ZH + (N_ROWS*DDIM/2))       // bf16 z lo
#define OFF_CBH     (OFF_ZL + (N_ROWS*DDIM/2))       // bf16 cb hi [8192*512]
#define OFF_CBL     (OFF_CBH + (KCODES*DDIM/2))      // bf16 cb lo
#define OFF_CBT     (OFF_CBL + (KCODES*DDIM/2))      // bf16 cb^T  [512*8192]
#define WS_FLOATS   (OFF_CBT + (DDIM*KCODES/2))      // ~168MB

typedef __attribute__((ext_vector_type(8))) short short8;
typedef __attribute__((ext_vector_type(4))) float f32x4;

__device__ __forceinline__ unsigned short f2bf(float x) {
    uint32_t u = __float_as_uint(x);
    u += 0x7fffu + ((u >> 16) & 1u);
    return (unsigned short)(u >> 16);
}

// async global->LDS, 16B per lane; lds base wave-uniform, lane i -> +i*16.
__device__ __forceinline__ void cp16(const unsigned short* g, unsigned short* l) {
    __builtin_amdgcn_global_load_lds(
        (const __attribute__((address_space(1))) void*)g,
        (__attribute__((address_space(3))) void*)l, 16, 0, 0);
}

// ---------------- JAX threefry2x32-20, key(42) = (0,42) ----------------
__device__ __forceinline__ uint32_t rotl32(uint32_t x, int r) {
    return (x << r) | (x >> (32 - r));
}

__device__ __forceinline__ void threefry2(uint32_t c0, uint32_t c1,
                                          uint32_t& o0, uint32_t& o1) {
    const uint32_t ks0 = 0u, ks1 = 42u, ks2 = 0x1BD11BDAu ^ 0u ^ 42u;
    uint32_t x0 = c0 + ks0;
    uint32_t x1 = c1 + ks1;
#define TF_R(r) { x0 += x1; x1 = rotl32(x1, r); x1 ^= x0; }
    TF_R(13) TF_R(15) TF_R(26) TF_R(6)
    x0 += ks1; x1 += ks2 + 1u;
    TF_R(17) TF_R(29) TF_R(16) TF_R(24)
    x0 += ks2; x1 += ks0 + 2u;
    TF_R(13) TF_R(15) TF_R(26) TF_R(6)
    x0 += ks0; x1 += ks1 + 3u;
    TF_R(17) TF_R(29) TF_R(16) TF_R(24)
    x0 += ks1; x1 += ks2 + 4u;
    TF_R(13) TF_R(15) TF_R(26) TF_R(6)
    x0 += ks2; x1 += ks0 + 5u;
#undef TF_R
    o0 = x0; o1 = x1;
}

__device__ __forceinline__ float u01(uint32_t bits) {
    return __uint_as_float((bits >> 9) | 0x3f800000u) - 1.0f;
}

__device__ __forceinline__ float gum(uint32_t bits) {
    float u = u01(bits);
    return -__logf(-__logf(u + 1e-10f) + 1e-10f);
}

// ---------------- block reduce helpers (256 threads = 4 waves) ----------------
__device__ __forceinline__ float blockReduce1(float v, float* red) {
    #pragma unroll
    for (int o = 32; o > 0; o >>= 1) v += __shfl_down(v, o);
    __syncthreads();
    if ((threadIdx.x & 63) == 0) red[threadIdx.x >> 6] = v;
    __syncthreads();
    return red[0] + red[1] + red[2] + red[3];
}

__device__ __forceinline__ void red2max(float& a, float& b, float* red) {
    #pragma unroll
    for (int o = 32; o > 0; o >>= 1) {
        a = fmaxf(a, __shfl_down(a, o));
        b = fmaxf(b, __shfl_down(b, o));
    }
    __syncthreads();
    if ((threadIdx.x & 63) == 0) {
        red[(threadIdx.x >> 6) * 2 + 0] = a;
        red[(threadIdx.x >> 6) * 2 + 1] = b;
    }
    __syncthreads();
    a = fmaxf(fmaxf(red[0], red[2]), fmaxf(red[4], red[6]));
    b = fmaxf(fmaxf(red[1], red[3]), fmaxf(red[5], red[7]));
}

__device__ __forceinline__ void red3sum(float& a, float& b, float& c, float* red) {
    #pragma unroll
    for (int o = 32; o > 0; o >>= 1) {
        a += __shfl_down(a, o);
        b += __shfl_down(b, o);
        c += __shfl_down(c, o);
    }
    __syncthreads();
    if ((threadIdx.x & 63) == 0) {
        red[(threadIdx.x >> 6) * 3 + 0] = a;
        red[(threadIdx.x >> 6) * 3 + 1] = b;
        red[(threadIdx.x >> 6) * 3 + 2] = c;
    }
    __syncthreads();
    a = red[0] + red[3] + red[6] + red[9];
    b = red[1] + red[4] + red[7] + red[10];
    c = red[2] + red[5] + red[8] + red[11];
}

// ---------------- K1: fused prep ----------------
// blocks [0,1024):    split z  -> zh/zl
// blocks [1024,3072): split cb -> cbh/cbl + cnorm (wave = one cb row)
// blocks [3072,4096): transpose cb -> cbT bf16
// block  4096:        zero accp (incl. ticket counter)
__global__ __launch_bounds__(256) void k_prep(const float* __restrict__ z,
                                              const float* __restrict__ cb,
                                              unsigned short* __restrict__ zh,
                                              unsigned short* __restrict__ zl,
                                              unsigned short* __restrict__ cbh,
                                              unsigned short* __restrict__ cbl,
                                              unsigned short* __restrict__ cbT,
                                              float* __restrict__ cnorm,
                                              float* __restrict__ accp) {
    __shared__ unsigned short TT[64][65];
    const int b = blockIdx.x;
    const int t = threadIdx.x;
    if (b < 3072) {
        const bool isz = (b < 1024);
        const int bb = isz ? b : b - 1024;
        const float* src = isz ? z : cb;
        unsigned short* hi = isz ? zh : cbh;
        unsigned short* lo = isz ? zl : cbl;
        const size_t idx = ((size_t)bb * 256 + t) * 8;
        float4 a = *(const float4*)(src + idx);
        float4 bv = *(const float4*)(src + idx + 4);
        float f[8] = {a.x, a.y, a.z, a.w, bv.x, bv.y, bv.z, bv.w};
        unsigned short h8[8], l8[8];
        float s = 0.f;
        #pragma unroll
        for (int e = 0; e < 8; ++e) {
            unsigned short h = f2bf(f[e]);
            float hf = __uint_as_float((uint32_t)h << 16);
            h8[e] = h;
            l8[e] = f2bf(f[e] - hf);
            s += f[e] * f[e];
        }
        *(short8*)(hi + idx) = *(short8*)h8;
        *(short8*)(lo + idx) = *(short8*)l8;
        if (!isz) {
            #pragma unroll
            for (int o = 32; o > 0; o >>= 1) s += __shfl_down(s, o);
            if ((t & 63) == 0) cnorm[bb * 4 + (t >> 6)] = s;
        }
    } else if (b < 4096) {
        const int b3 = b - 3072;
        const int k0 = (b3 & 127) * 64;
        const int d0 = (b3 >> 7) * 64;
        #pragma unroll
        for (int j = 0; j < 4; ++j) {
            const int unit = t + j * 256;
            const int r = unit >> 4;
            const int s4 = unit & 15;
            float4 v = *(const float4*)(cb + (size_t)(k0 + r) * DDIM + d0 + s4 * 4);
            TT[r][s4*4+0] = f2bf(v.x); TT[r][s4*4+1] = f2bf(v.y);
            TT[r][s4*4+2] = f2bf(v.z); TT[r][s4*4+3] = f2bf(v.w);
        }
        __syncthreads();
        #pragma unroll
        for (int j = 0; j < 2; ++j) {
            const int unit = t + j * 256;
            const int dr = unit >> 3;
            const int ks = (unit & 7) * 8;
            unsigned short o8[8];
            #pragma unroll
            for (int i = 0; i < 8; ++i) o8[i] = TT[ks + i][dr];
            *(short8*)(cbT + (size_t)(d0 + dr) * KCODES + k0 + ks) = *(short8*)o8;
        }
    } else {
        if (t < 4) accp[t] = 0.f;
    }
}

// ---------------- K2: GEMM1 (MFMA, async LDS staging, bf16 3-term) ----------
// 128x128 tile, BK=32. At the 2-barrier-structure plateau (~31% MfmaUtil);
// pad (R4) and async staging (R5) measured neutral. Parked.
#define BK1 32
__global__ __launch_bounds__(256) void k_gemm1(const unsigned short* __restrict__ zh,
                                               const unsigned short* __restrict__ zl,
                                               const unsigned short* __restrict__ cbh,
                                               const unsigned short* __restrict__ cbl,
                                               const float* __restrict__ cnorm,
                                               const float* __restrict__ var_q,
                                               float* __restrict__ logit) {
    __shared__ __align__(16) unsigned short AH[128 * BK1];
    __shared__ __align__(16) unsigned short AL[128 * BK1];
    __shared__ __align__(16) unsigned short BH[128 * BK1];
    __shared__ __align__(16) unsigned short BL[128 * BK1];
    const int t    = threadIdx.x;
    const int n0   = blockIdx.x * 128;
    const int m0   = blockIdx.y * 128;
    const int w    = t >> 6;
    const int lane = t & 63;
    const int wm   = (w >> 1) * 64;
    const int wn   = (w & 1) * 64;
    const int lrow = lane & 15;
    const int lq   = lane >> 4;

    const unsigned short* src;
    unsigned short* dst;
    if      (w == 0) { src = zh;  dst = AH; }
    else if (w == 1) { src = zl;  dst = AL; }
    else if (w == 2) { src = cbh; dst = BH; }
    else             { src = cbl; dst = BL; }
    const int brow = (w < 2) ? m0 : n0;
    const unsigned short* gsrc = src + (size_t)(brow + (lane >> 2)) * DDIM + (lane & 3) * 8;

    f32x4 acc[4][4];
    #pragma unroll
    for (int i = 0; i < 4; ++i)
        #pragma unroll
        for (int j = 0; j < 4; ++j)
            acc[i][j] = (f32x4){0.f, 0.f, 0.f, 0.f};

    for (int kt = 0; kt < DDIM; kt += BK1) {
        __syncthreads();
        #pragma unroll
        for (int j = 0; j < 8; ++j)
            cp16(gsrc + (size_t)j * 16 * DDIM + kt, dst + j * 512);
        __syncthreads();

        short8 ah[4], al[4], bh[4], bl[4];
        #pragma unroll
        for (int mt = 0; mt < 4; ++mt) {
            const int row = wm + mt * 16 + lrow;
            ah[mt] = *(const short8*)&AH[row * BK1 + lq * 8];
            al[mt] = *(const short8*)&AL[row * BK1 + lq * 8];
        }
        #pragma unroll
        for (int nt = 0; nt < 4; ++nt) {
            const int row = wn + nt * 16 + lrow;
            bh[nt] = *(const short8*)&BH[row * BK1 + lq * 8];
            bl[nt] = *(const short8*)&BL[row * BK1 + lq * 8];
        }
        #pragma unroll
        for (int mt = 0; mt < 4; ++mt)
            #pragma unroll
            for (int nt = 0; nt < 4; ++nt) {
                acc[mt][nt] = __builtin_amdgcn_mfma_f32_16x16x32_bf16(ah[mt], bh[nt], acc[mt][nt], 0, 0, 0);
                acc[mt][nt] = __builtin_amdgcn_mfma_f32_16x16x32_bf16(ah[mt], bl[nt], acc[mt][nt], 0, 0, 0);
                acc[mt][nt] = __builtin_amdgcn_mfma_f32_16x16x32_bf16(al[mt], bh[nt], acc[mt][nt], 0, 0, 0);
            }
    }

    const float wq = 0.5f / fmaxf(var_q[0], 1e-10f);
    #pragma unroll
    for (int nt = 0; nt < 4; ++nt) {
        const int gcol = n0 + wn + nt * 16 + lrow;
        const float cn = cnorm[gcol];
        #pragma unroll
        for (int mt = 0; mt < 4; ++mt) {
            #pragma unroll
            for (int r = 0; r < 4; ++r) {
                const int grow = m0 + wm + mt * 16 + lq * 4 + r;
                logit[(size_t)grow * KCODES + gcol] = wq * (2.0f * acc[mt][nt][r] - cn);
            }
        }
    }
}

// ---------------- K3: fused stats + colsum + encodings ----------------
// 1024 blocks, 2 row-pairs each (rows r=2b+i and r+2048).  One threefry per
// column serves both rows.  Colsum partials -> upper 16KB halves of logit
// slots 2b and 2b+1.
#define PROCESS_ROW(rr, garr)                                               \
  {                                                                         \
    const int rowi = (rr);                                                  \
    const float* lrowp = logit + (size_t)rowi * KCODES;                     \
    float l[32];                                                            \
    _Pragma("unroll")                                                       \
    for (int j = 0; j < 8; ++j) {                                           \
        float4 v = *(const float4*)(lrowp + t * 4 + j * 1024);              \
        l[j*4+0] = v.x; l[j*4+1] = v.y; l[j*4+2] = v.z; l[j*4+3] = v.w;     \
    }                                                                       \
    float m1 = -3.0e38f, m2 = -3.0e38f;                                     \
    _Pragma("unroll")                                                       \
    for (int e = 0; e < 32; ++e) {                                          \
        m1 = fmaxf(m1, l[e]);                                               \
        m2 = fmaxf(m2, (l[e] + garr[e]) * 2.0f);                            \
    }                                                                       \
    red2max(m1, m2, red);                                                   \
    float s1 = 0.f, t1 = 0.f, s2 = 0.f;                                     \
    _Pragma("unroll")                                                       \
    for (int e = 0; e < 32; ++e) {                                          \
        float x  = l[e] - m1;                                               \
        float y  = (l[e] + garr[e]) * 2.0f - m2;                            \
        float e1 = __expf(x);                                               \
        float e2 = __expf(y);                                               \
        s1 += e1; t1 += e1 * x; s2 += e2;                                   \
        l[e] = e1; garr[e] = e2;                                            \
    }                                                                       \
    red3sum(s1, t1, s2, red);                                               \
    const float is1 = 1.0f / s1, is2 = 1.0f / s2;                           \
    unsigned short o16[32];                                                 \
    _Pragma("unroll")                                                       \
    for (int e = 0; e < 32; ++e) {                                          \
        csum[e] += l[e] * is1;                                              \
        o16[e] = f2bf(garr[e] * is2);                                       \
    }                                                                       \
    unsigned short* dstp = (unsigned short*)logit + (size_t)rowi * (2 * KCODES); \
    _Pragma("unroll")                                                       \
    for (int j = 0; j < 8; ++j)                                             \
        *(ushort4*)(dstp + t * 4 + j * 1024) = *(ushort4*)&o16[j * 4];      \
    if (t == 0) kld += t1 * is1 - __logf(s1);                               \
  }

__global__ __launch_bounds__(256) void k_fused(float* __restrict__ logit,
                                               float* __restrict__ acc) {
    __shared__ float red[12];
    __shared__ float ghi[KCODES];   // pending gumbels for row r+2048
    const int b = blockIdx.x;       // 0..1023
    const int t = threadIdx.x;
    float csum[32];
    #pragma unroll
    for (int e = 0; e < 32; ++e) csum[e] = 0.f;
    float kld = 0.f;

    for (int i = 0; i < 2; ++i) {
        const int r_lo = b * 2 + i;       // < 2048
        const int r_hi = r_lo + 2048;

        float g_lo[32];
        #pragma unroll
        for (int j = 0; j < 8; ++j)
            #pragma unroll
            for (int e4 = 0; e4 < 4; ++e4) {
                const uint32_t col = (uint32_t)(t * 4 + j * 1024 + e4);
                const uint32_t jg  = (uint32_t)r_lo * (uint32_t)KCODES + col;
                uint32_t b0, b1;
                threefry2(jg, jg + HALF_NK, b0, b1);
                g_lo[j*4+e4] = gum(b0);
                ghi[col] = gum(b1);       // thread-private slot, no barrier needed
            }

        PROCESS_ROW(r_lo, g_lo)

        float g_hi[32];
        #pragma unroll
        for (int j = 0; j < 8; ++j)
            #pragma unroll
            for (int e4 = 0; e4 < 4; ++e4)
                g_hi[j*4+e4] = ghi[t * 4 + j * 1024 + e4];

        PROCESS_ROW(r_hi, g_hi)
    }

    // spill colsum partials: col c -> slot (2b + c/4096), offset 4096 + c%4096
    #pragma unroll
    for (int j = 0; j < 8; ++j) {
        const int c = t * 4 + j * 1024;
        float* dstp = logit + (size_t)(2 * b + (c >> 12)) * KCODES + 4096 + (c & 4095);
        *(float4*)dstp = make_float4(csum[j*4], csum[j*4+1], csum[j*4+2], csum[j*4+3]);
    }
    if (t == 0) atomicAdd(acc + 0, kld);
}

// ---------------- K4: GEMM2 z_hat = enc16 @ cbT^T (R8-proven shape, pure) ---
// 256 thr (4 waves 2x2), 64x128 tile, BK=64, ksplit=2 -> 512 blocks = 2/CU.
// z=0 -> outA partial, z=1 -> out partial (no atomics, no memset).
// NO serial epilogue here: a straggler epilogue on a subset of blocks
// extends the whole dispatch (R10: +39 us). Entropy lives in k_tail.
#define BK2 64
__global__ __launch_bounds__(256) void k_gemm2(const unsigned short* __restrict__ enc16,
                                               const unsigned short* __restrict__ cbT,
                                               float* __restrict__ outA,
                                               float* __restrict__ out) {
    __shared__ __align__(16) unsigned short AS[64 * BK2];    // 8 KB
    __shared__ __align__(16) unsigned short BS[128 * BK2];   // 16 KB
    const int t    = threadIdx.x;
    const int n0   = blockIdx.x * 128;          // grid.x = 4
    const int m0   = blockIdx.y * 64;           // grid.y = 64
    const int kz0  = blockIdx.z * (KCODES / 2); // ksplit 2
    float* dstC    = blockIdx.z ? out : outA;
    const int w    = t >> 6;
    const int lane = t & 63;
    const int wm   = (w >> 1) * 32;
    const int wn   = (w & 1) * 64;
    const int lrow = lane & 15;
    const int lq   = lane >> 4;
    const int srow = lane >> 3;        // staging row within 8-row chunk
    const int scol = (lane & 7) * 8;   // staging k-offset (shorts)

    const unsigned short* Asrc = enc16 + (size_t)(m0 + srow) * (2 * KCODES) + scol;
    const unsigned short* Bsrc = cbT   + (size_t)(n0 + srow) * KCODES + scol;

    f32x4 acc4[2][4];
    #pragma unroll
    for (int i = 0; i < 2; ++i)
        #pragma unroll
        for (int j = 0; j < 4; ++j)
            acc4[i][j] = (f32x4){0.f, 0.f, 0.f, 0.f};

    for (int kt = kz0; kt < kz0 + KCODES / 2; kt += BK2) {
        __syncthreads();
        #pragma unroll
        for (int j = 0; j < 2; ++j) {
            const int ja = w * 2 + j;
            cp16(Asrc + (size_t)(ja * 8) * (2 * KCODES) + kt, AS + ja * 512);
        }
        #pragma unroll
        for (int j = 0; j < 4; ++j) {
            const int jb = w * 4 + j;
            cp16(Bsrc + (size_t)(jb * 8) * KCODES + kt, BS + jb * 512);
        }
        __syncthreads();

        #pragma unroll
        for (int chunk = 0; chunk < 2; ++chunk) {
            short8 af[2];
            #pragma unroll
            for (int mt = 0; mt < 2; ++mt)
                af[mt] = *(const short8*)&AS[(wm + mt * 16 + lrow) * BK2 + chunk * 32 + lq * 8];
            #pragma unroll
            for (int nt = 0; nt < 4; ++nt) {
                const short8 bf = *(const short8*)&BS[(wn + nt * 16 + lrow) * BK2 + chunk * 32 + lq * 8];
                #pragma unroll
                for (int mt = 0; mt < 2; ++mt)
                    acc4[mt][nt] = __builtin_amdgcn_mfma_f32_16x16x32_bf16(af[mt], bf, acc4[mt][nt], 0, 0, 0);
            }
        }
    }

    #pragma unroll
    for (int mt = 0; mt < 2; ++mt)
        #pragma unroll
        for (int nt = 0; nt < 4; ++nt)
            #pragma unroll
            for (int r = 0; r < 4; ++r) {
                const int grow = m0 + wm + mt * 16 + lq * 4 + r;
                const int gcol = n0 + wn + nt * 16 + lrow;
                dstC[(size_t)grow * DDIM + gcol] = acc4[mt][nt][r];
            }
}

// ---------------- K5: tail (entropy + combine + cont. KLD + ticket) ---------
// blocks [0,32):   column-sum entropy over the 1024 colsum partials
//                  (4-way unrolled independent accumulators for ILP; runs
//                  concurrently with the 512 combine blocks)
// blocks [32,544): out = out + outA, accumulate (z-zhat)^2
// last of all 544 blocks (device ticket) finalizes loss + perplexity.
__global__ __launch_bounds__(256) void k_tail(const float* __restrict__ part,
                                              const float* __restrict__ z,
                                              const float* __restrict__ outA,
                                              const float* __restrict__ var_q,
                                              float* __restrict__ out,
                                              float* __restrict__ acc) {
    __shared__ float red[4];
    const int b = blockIdx.x;
    const int t = threadIdx.x;
    if (b < 32) {
        const int col = b * 256 + t;
        const size_t off = (size_t)(col >> 12) * KCODES + 4096 + (col & 4095);
        float s0 = 0.f, s1 = 0.f, s2 = 0.f, s3 = 0.f;
        for (int bb = 0; bb < 1024; bb += 4) {
            s0 += part[(size_t)(2 * (bb + 0)) * KCODES + off];
            s1 += part[(size_t)(2 * (bb + 1)) * KCODES + off];
            s2 += part[(size_t)(2 * (bb + 2)) * KCODES + off];
            s3 += part[(size_t)(2 * (bb + 3)) * KCODES + off];
        }
        float a = ((s0 + s1) + (s2 + s3)) * INV_N;
        float ent = a * __logf(a + 1e-7f);
        ent = blockReduce1(ent, red);
        if (t == 0) atomicAdd(acc + 2, ent);
    } else {
        const size_t base = (size_t)(b - 32) * 4096 + t * 4;
        float p = 0.f;
        #pragma unroll
        for (int j = 0; j < 4; ++j) {
            const size_t idx = base + j * 1024;
            float4 o1 = *(const float4*)(out + idx);
            float4 o2 = *(const float4*)(outA + idx);
            float4 zv = *(const float4*)(z + idx);
            float4 s4;
            s4.x = o1.x + o2.x; s4.y = o1.y + o2.y;
            s4.z = o1.z + o2.z; s4.w = o1.w + o2.w;
            *(float4*)(out + idx) = s4;
            float dx = zv.x - s4.x, dy = zv.y - s4.y;
            float dz = zv.z - s4.z, dw = zv.w - s4.w;
            p += dx*dx + dy*dy + dz*dz + dw*dw;
        }
        p = blockReduce1(p, red);
        if (t == 0) atomicAdd(acc + 1, p);
    }
    // ticket: last of ALL 544 blocks finalizes (entropy + loss complete)
    if (t == 0) {
        __threadfence();
        unsigned* cnt = (unsigned*)(acc + 3);
        if (atomicAdd(cnt, 1u) == 543u) {
            float a0 = atomicAdd(acc + 0, 0.f);
            float a1 = atomicAdd(acc + 1, 0.f);
            float a2 = atomicAdd(acc + 2, 0.f);
            float wq = 0.5f / fmaxf(var_q[0], 1e-10f);
            out[(size_t)N_ROWS * DDIM]     = a0 / BS_F + a1 * wq / BS_F;
            out[(size_t)N_ROWS * DDIM + 1] = expf(-a2);
        }
    }
}

// ---------------- launch ----------------
extern "C" void kernel_launch(void* const* d_in, const int* in_sizes, int n_in,
                              void* d_out, int out_size, void* d_ws, size_t ws_size,
                              hipStream_t stream) {
    const float* z     = (const float*)d_in[0];
    const float* var_q = (const float*)d_in[1];
    const float* cb    = (const float*)d_in[2];
    float* out = (float*)d_out;
    float* ws  = (float*)d_ws;
    if (ws_size < (size_t)WS_FLOATS * sizeof(float)) return;  // need ~168 MB

    float* logit  = ws + OFF_LOGIT;
    float* cnorm  = ws + OFF_CNORM;
    float* accp   = ws + OFF_ACC;
    unsigned short* zh  = (unsigned short*)(ws + OFF_ZH);
    unsigned short* zl  = (unsigned short*)(ws + OFF_ZL);
    unsigned short* cbh = (unsigned short*)(ws + OFF_CBH);
    unsigned short* cbl = (unsigned short*)(ws + OFF_CBL);
    unsigned short* cbT = (unsigned short*)(ws + OFF_CBT);
    float* outA = ws + OFF_CBL;   // cbl reused after gemm1 (8MB = 4096*512*4B)

    k_prep  <<<4097, 256, 0, stream>>>(z, cb, zh, zl, cbh, cbl, cbT, cnorm, accp);
    k_gemm1 <<<dim3(KCODES / 128, N_ROWS / 128), 256, 0, stream>>>(zh, zl, cbh, cbl, cnorm, var_q, logit);
    k_fused <<<1024, 256, 0, stream>>>(logit, accp);
    k_gemm2 <<<dim3(DDIM / 128, N_ROWS / 64, 2), 256, 0, stream>>>((const unsigned short*)logit, cbT, outA, out);
    k_tail  <<<544, 256, 0, stream>>>(logit, z, outA, var_q, out, accp);
}

// Round 12
// 492.287 us; speedup vs baseline: 1.0347x; 1.0347x over previous
//
#include <hip/hip_runtime.h>
#include <stdint.h>

// ---------------- problem constants ----------------
#define N_ROWS 4096      // bs*seq = 8*512
#define DDIM   512
#define KCODES 8192
#define NK     (N_ROWS * KCODES)   // 33,554,432
#define HALF_NK 16777216u
#define BS_F   8.0f
#define INV_N  (1.0f / 4096.0f)

// ---------------- ws layout (float offsets) ----------------
// logit region (NK floats): after k_fused, row n's bf16 encodings live in the
// FIRST 16KB of row n's 32KB slot (upper halves now unused — colsum is atomic).
// cbl (8MB) is DEAD after k_gemm1 -> reused as outA (gemm2 k-split partial 0).
#define OFF_LOGIT   0
#define OFF_CNORM   (NK)
#define OFF_ACC     (OFF_CNORM + KCODES)   // [0]=sum p*logp [1]=sum(z-zhat)^2 [2]=entropy [3]=ticket
#define OFF_COLSUM  (OFF_ACC + 4)          // colsum[8192], atomic accumulation
#define OFF_ZH      (OFF_COLSUM + KCODES)            // bf16 z hi  [4096*512]
#define OFF_ZL      (OFF_ZH + (N_ROWS*DDIM/2))       // bf16 z lo
#define OFF_CBH     (OFF_ZL + (N_ROWS*DDIM/2))       // bf16 cb hi [8192*512]
#define OFF_CBL     (OFF_CBH + (KCODES*DDIM/2))      // bf16 cb lo
#define OFF_CBT     (OFF_CBL + (KCODES*DDIM/2))      // bf16 cb^T  [512*8192]
#define WS_FLOATS   (OFF_CBT + (DDIM*KCODES/2))      // ~168MB

typedef __attribute__((ext_vector_type(8))) short short8;
typedef __attribute__((ext_vector_type(4))) float f32x4;

__device__ __forceinline__ unsigned short f2bf(float x) {
    uint32_t u = __float_as_uint(x);
    u += 0x7fffu + ((u >> 16) & 1u);
    return (unsigned short)(u >> 16);
}

// async global->LDS, 16B per lane; lds base wave-uniform, lane i -> +i*16.
__device__ __forceinline__ void cp16(const unsigned short* g, unsigned short* l) {
    __builtin_amdgcn_global_load_lds(
        (const __attribute__((address_space(1))) void*)g,
        (__attribute__((address_space(3))) void*)l, 16, 0, 0);
}

// ---------------- JAX threefry2x32-20, key(42) = (0,42) ----------------
__device__ __forceinline__ uint32_t rotl32(uint32_t x, int r) {
    return (x << r) | (x >> (32 - r));
}

__device__ __forceinline__ void threefry2(uint32_t c0, uint32_t c1,
                                          uint32_t& o0, uint32_t& o1) {
    const uint32_t ks0 = 0u, ks1 = 42u, ks2 = 0x1BD11BDAu ^ 0u ^ 42u;
    uint32_t x0 = c0 + ks0;
    uint32_t x1 = c1 + ks1;
#define TF_R(r) { x0 += x1; x1 = rotl32(x1, r); x1 ^= x0; }
    TF_R(13) TF_R(15) TF_R(26) TF_R(6)
    x0 += ks1; x1 += ks2 + 1u;
    TF_R(17) TF_R(29) TF_R(16) TF_R(24)
    x0 += ks2; x1 += ks0 + 2u;
    TF_R(13) TF_R(15) TF_R(26) TF_R(6)
    x0 += ks0; x1 += ks1 + 3u;
    TF_R(17) TF_R(29) TF_R(16) TF_R(24)
    x0 += ks1; x1 += ks2 + 4u;
    TF_R(13) TF_R(15) TF_R(26) TF_R(6)
    x0 += ks2; x1 += ks0 + 5u;
#undef TF_R
    o0 = x0; o1 = x1;
}

__device__ __forceinline__ float u01(uint32_t bits) {
    return __uint_as_float((bits >> 9) | 0x3f800000u) - 1.0f;
}

__device__ __forceinline__ float gum(uint32_t bits) {
    float u = u01(bits);
    return -__logf(-__logf(u + 1e-10f) + 1e-10f);
}

// ---------------- block reduce helpers (256 threads = 4 waves) ----------------
__device__ __forceinline__ float blockReduce1(float v, float* red) {
    #pragma unroll
    for (int o = 32; o > 0; o >>= 1) v += __shfl_down(v, o);
    __syncthreads();
    if ((threadIdx.x & 63) == 0) red[threadIdx.x >> 6] = v;
    __syncthreads();
    return red[0] + red[1] + red[2] + red[3];
}

__device__ __forceinline__ void red2max(float& a, float& b, float* red) {
    #pragma unroll
    for (int o = 32; o > 0; o >>= 1) {
        a = fmaxf(a, __shfl_down(a, o));
        b = fmaxf(b, __shfl_down(b, o));
    }
    __syncthreads();
    if ((threadIdx.x & 63) == 0) {
        red[(threadIdx.x >> 6) * 2 + 0] = a;
        red[(threadIdx.x >> 6) * 2 + 1] = b;
    }
    __syncthreads();
    a = fmaxf(fmaxf(red[0], red[2]), fmaxf(red[4], red[6]));
    b = fmaxf(fmaxf(red[1], red[3]), fmaxf(red[5], red[7]));
}

__device__ __forceinline__ void red3sum(float& a, float& b, float& c, float* red) {
    #pragma unroll
    for (int o = 32; o > 0; o >>= 1) {
        a += __shfl_down(a, o);
        b += __shfl_down(b, o);
        c += __shfl_down(c, o);
    }
    __syncthreads();
    if ((threadIdx.x & 63) == 0) {
        red[(threadIdx.x >> 6) * 3 + 0] = a;
        red[(threadIdx.x >> 6) * 3 + 1] = b;
        red[(threadIdx.x >> 6) * 3 + 2] = c;
    }
    __syncthreads();
    a = red[0] + red[3] + red[6] + red[9];
    b = red[1] + red[4] + red[7] + red[10];
    c = red[2] + red[5] + red[8] + red[11];
}

// ---------------- K1: fused prep ----------------
// blocks [0,1024):    split z  -> zh/zl
// blocks [1024,3072): split cb -> cbh/cbl + cnorm (wave = one cb row)
// blocks [3072,4096): transpose cb -> cbT bf16
// block  4096:        zero accp + colsum
__global__ __launch_bounds__(256) void k_prep(const float* __restrict__ z,
                                              const float* __restrict__ cb,
                                              unsigned short* __restrict__ zh,
                                              unsigned short* __restrict__ zl,
                                              unsigned short* __restrict__ cbh,
                                              unsigned short* __restrict__ cbl,
                                              unsigned short* __restrict__ cbT,
                                              float* __restrict__ cnorm,
                                              float* __restrict__ accp,
                                              float* __restrict__ colsum) {
    __shared__ unsigned short TT[64][65];
    const int b = blockIdx.x;
    const int t = threadIdx.x;
    if (b < 3072) {
        const bool isz = (b < 1024);
        const int bb = isz ? b : b - 1024;
        const float* src = isz ? z : cb;
        unsigned short* hi = isz ? zh : cbh;
        unsigned short* lo = isz ? zl : cbl;
        const size_t idx = ((size_t)bb * 256 + t) * 8;
        float4 a = *(const float4*)(src + idx);
        float4 bv = *(const float4*)(src + idx + 4);
        float f[8] = {a.x, a.y, a.z, a.w, bv.x, bv.y, bv.z, bv.w};
        unsigned short h8[8], l8[8];
        float s = 0.f;
        #pragma unroll
        for (int e = 0; e < 8; ++e) {
            unsigned short h = f2bf(f[e]);
            float hf = __uint_as_float((uint32_t)h << 16);
            h8[e] = h;
            l8[e] = f2bf(f[e] - hf);
            s += f[e] * f[e];
        }
        *(short8*)(hi + idx) = *(short8*)h8;
        *(short8*)(lo + idx) = *(short8*)l8;
        if (!isz) {
            #pragma unroll
            for (int o = 32; o > 0; o >>= 1) s += __shfl_down(s, o);
            if ((t & 63) == 0) cnorm[bb * 4 + (t >> 6)] = s;
        }
    } else if (b < 4096) {
        const int b3 = b - 3072;
        const int k0 = (b3 & 127) * 64;
        const int d0 = (b3 >> 7) * 64;
        #pragma unroll
        for (int j = 0; j < 4; ++j) {
            const int unit = t + j * 256;
            const int r = unit >> 4;
            const int s4 = unit & 15;
            float4 v = *(const float4*)(cb + (size_t)(k0 + r) * DDIM + d0 + s4 * 4);
            TT[r][s4*4+0] = f2bf(v.x); TT[r][s4*4+1] = f2bf(v.y);
            TT[r][s4*4+2] = f2bf(v.z); TT[r][s4*4+3] = f2bf(v.w);
        }
        __syncthreads();
        #pragma unroll
        for (int j = 0; j < 2; ++j) {
            const int unit = t + j * 256;
            const int dr = unit >> 3;
            const int ks = (unit & 7) * 8;
            unsigned short o8[8];
            #pragma unroll
            for (int i = 0; i < 8; ++i) o8[i] = TT[ks + i][dr];
            *(short8*)(cbT + (size_t)(d0 + dr) * KCODES + k0 + ks) = *(short8*)o8;
        }
    } else {
        if (t < 4) accp[t] = 0.f;
        #pragma unroll
        for (int j = 0; j < 32; ++j) colsum[t + j * 256] = 0.f;
    }
}

// ---------------- K2: GEMM1 (MFMA, async LDS staging, bf16 3-term) ----------
// 128x128 tile, BK=32. At the 2-barrier-structure plateau (~31% MfmaUtil);
// pad (R4) and async staging (R5) measured neutral. Parked.
#define BK1 32
__global__ __launch_bounds__(256) void k_gemm1(const unsigned short* __restrict__ zh,
                                               const unsigned short* __restrict__ zl,
                                               const unsigned short* __restrict__ cbh,
                                               const unsigned short* __restrict__ cbl,
                                               const float* __restrict__ cnorm,
                                               const float* __restrict__ var_q,
                                               float* __restrict__ logit) {
    __shared__ __align__(16) unsigned short AH[128 * BK1];
    __shared__ __align__(16) unsigned short AL[128 * BK1];
    __shared__ __align__(16) unsigned short BH[128 * BK1];
    __shared__ __align__(16) unsigned short BL[128 * BK1];
    const int t    = threadIdx.x;
    const int n0   = blockIdx.x * 128;
    const int m0   = blockIdx.y * 128;
    const int w    = t >> 6;
    const int lane = t & 63;
    const int wm   = (w >> 1) * 64;
    const int wn   = (w & 1) * 64;
    const int lrow = lane & 15;
    const int lq   = lane >> 4;

    const unsigned short* src;
    unsigned short* dst;
    if      (w == 0) { src = zh;  dst = AH; }
    else if (w == 1) { src = zl;  dst = AL; }
    else if (w == 2) { src = cbh; dst = BH; }
    else             { src = cbl; dst = BL; }
    const int brow = (w < 2) ? m0 : n0;
    const unsigned short* gsrc = src + (size_t)(brow + (lane >> 2)) * DDIM + (lane & 3) * 8;

    f32x4 acc[4][4];
    #pragma unroll
    for (int i = 0; i < 4; ++i)
        #pragma unroll
        for (int j = 0; j < 4; ++j)
            acc[i][j] = (f32x4){0.f, 0.f, 0.f, 0.f};

    for (int kt = 0; kt < DDIM; kt += BK1) {
        __syncthreads();
        #pragma unroll
        for (int j = 0; j < 8; ++j)
            cp16(gsrc + (size_t)j * 16 * DDIM + kt, dst + j * 512);
        __syncthreads();

        short8 ah[4], al[4], bh[4], bl[4];
        #pragma unroll
        for (int mt = 0; mt < 4; ++mt) {
            const int row = wm + mt * 16 + lrow;
            ah[mt] = *(const short8*)&AH[row * BK1 + lq * 8];
            al[mt] = *(const short8*)&AL[row * BK1 + lq * 8];
        }
        #pragma unroll
        for (int nt = 0; nt < 4; ++nt) {
            const int row = wn + nt * 16 + lrow;
            bh[nt] = *(const short8*)&BH[row * BK1 + lq * 8];
            bl[nt] = *(const short8*)&BL[row * BK1 + lq * 8];
        }
        #pragma unroll
        for (int mt = 0; mt < 4; ++mt)
            #pragma unroll
            for (int nt = 0; nt < 4; ++nt) {
                acc[mt][nt] = __builtin_amdgcn_mfma_f32_16x16x32_bf16(ah[mt], bh[nt], acc[mt][nt], 0, 0, 0);
                acc[mt][nt] = __builtin_amdgcn_mfma_f32_16x16x32_bf16(ah[mt], bl[nt], acc[mt][nt], 0, 0, 0);
                acc[mt][nt] = __builtin_amdgcn_mfma_f32_16x16x32_bf16(al[mt], bh[nt], acc[mt][nt], 0, 0, 0);
            }
    }

    const float wq = 0.5f / fmaxf(var_q[0], 1e-10f);
    #pragma unroll
    for (int nt = 0; nt < 4; ++nt) {
        const int gcol = n0 + wn + nt * 16 + lrow;
        const float cn = cnorm[gcol];
        #pragma unroll
        for (int mt = 0; mt < 4; ++mt) {
            #pragma unroll
            for (int r = 0; r < 4; ++r) {
                const int grow = m0 + wm + mt * 16 + lq * 4 + r;
                logit[(size_t)grow * KCODES + gcol] = wq * (2.0f * acc[mt][nt][r] - cn);
            }
        }
    }
}

// ---------------- K3: fused stats + colsum + encodings ----------------
// 1024 blocks, 2 row-pairs each (rows r=2b+i and r+2048).  One threefry per
// column serves both rows.  Colsum goes straight to the atomic colsum[8192]
// (32KB, L2-resident; ~1024 adds/address spread over the kernel) — no
// partial-set spill, no serial reduction straggler (R11: 146us tail).
#define PROCESS_ROW(rr, garr)                                               \
  {                                                                         \
    const int rowi = (rr);                                                  \
    const float* lrowp = logit + (size_t)rowi * KCODES;                     \
    float l[32];                                                            \
    _Pragma("unroll")                                                       \
    for (int j = 0; j < 8; ++j) {                                           \
        float4 v = *(const float4*)(lrowp + t * 4 + j * 1024);              \
        l[j*4+0] = v.x; l[j*4+1] = v.y; l[j*4+2] = v.z; l[j*4+3] = v.w;     \
    }                                                                       \
    float m1 = -3.0e38f, m2 = -3.0e38f;                                     \
    _Pragma("unroll")                                                       \
    for (int e = 0; e < 32; ++e) {                                          \
        m1 = fmaxf(m1, l[e]);                                               \
        m2 = fmaxf(m2, (l[e] + garr[e]) * 2.0f);                            \
    }                                                                       \
    red2max(m1, m2, red);                                                   \
    float s1 = 0.f, t1 = 0.f, s2 = 0.f;                                     \
    _Pragma("unroll")                                                       \
    for (int e = 0; e < 32; ++e) {                                          \
        float x  = l[e] - m1;                                               \
        float y  = (l[e] + garr[e]) * 2.0f - m2;                            \
        float e1 = __expf(x);                                               \
        float e2 = __expf(y);                                               \
        s1 += e1; t1 += e1 * x; s2 += e2;                                   \
        l[e] = e1; garr[e] = e2;                                            \
    }                                                                       \
    red3sum(s1, t1, s2, red);                                               \
    const float is1 = 1.0f / s1, is2 = 1.0f / s2;                           \
    unsigned short o16[32];                                                 \
    _Pragma("unroll")                                                       \
    for (int e = 0; e < 32; ++e) {                                          \
        csum[e] += l[e] * is1;                                              \
        o16[e] = f2bf(garr[e] * is2);                                       \
    }                                                                       \
    unsigned short* dstp = (unsigned short*)logit + (size_t)rowi * (2 * KCODES); \
    _Pragma("unroll")                                                       \
    for (int j = 0; j < 8; ++j)                                             \
        *(ushort4*)(dstp + t * 4 + j * 1024) = *(ushort4*)&o16[j * 4];      \
    if (t == 0) kld += t1 * is1 - __logf(s1);                               \
  }

__global__ __launch_bounds__(256) void k_fused(float* __restrict__ logit,
                                               float* __restrict__ colsum,
                                               float* __restrict__ acc) {
    __shared__ float red[12];
    __shared__ float ghi[KCODES];   // pending gumbels for row r+2048
    const int b = blockIdx.x;       // 0..1023
    const int t = threadIdx.x;
    float csum[32];
    #pragma unroll
    for (int e = 0; e < 32; ++e) csum[e] = 0.f;
    float kld = 0.f;

    for (int i = 0; i < 2; ++i) {
        const int r_lo = b * 2 + i;       // < 2048
        const int r_hi = r_lo + 2048;

        float g_lo[32];
        #pragma unroll
        for (int j = 0; j < 8; ++j)
            #pragma unroll
            for (int e4 = 0; e4 < 4; ++e4) {
                const uint32_t col = (uint32_t)(t * 4 + j * 1024 + e4);
                const uint32_t jg  = (uint32_t)r_lo * (uint32_t)KCODES + col;
                uint32_t b0, b1;
                threefry2(jg, jg + HALF_NK, b0, b1);
                g_lo[j*4+e4] = gum(b0);
                ghi[col] = gum(b1);       // thread-private slot, no barrier needed
            }

        PROCESS_ROW(r_lo, g_lo)

        float g_hi[32];
        #pragma unroll
        for (int j = 0; j < 8; ++j)
            #pragma unroll
            for (int e4 = 0; e4 < 4; ++e4)
                g_hi[j*4+e4] = ghi[t * 4 + j * 1024 + e4];

        PROCESS_ROW(r_hi, g_hi)
    }

    // colsum: block-staggered order to avoid phase-aligned hotspots
    #pragma unroll
    for (int jj = 0; jj < 8; ++jj) {
        const int j = (jj + b) & 7;
        const int c = t * 4 + j * 1024;
        atomicAdd(&colsum[c + 0], csum[j*4 + 0]);
        atomicAdd(&colsum[c + 1], csum[j*4 + 1]);
        atomicAdd(&colsum[c + 2], csum[j*4 + 2]);
        atomicAdd(&colsum[c + 3], csum[j*4 + 3]);
    }
    if (t == 0) atomicAdd(acc + 0, kld);
}

// ---------------- K4: GEMM2 z_hat = enc16 @ cbT^T (R8-proven shape, pure) ---
// 256 thr (4 waves 2x2), 64x128 tile, BK=64, ksplit=2 -> 512 blocks = 2/CU.
// z=0 -> outA partial, z=1 -> out partial (no atomics, no memset).
// NO serial epilogue (R10 straggler lesson).
#define BK2 64
__global__ __launch_bounds__(256) void k_gemm2(const unsigned short* __restrict__ enc16,
                                               const unsigned short* __restrict__ cbT,
                                               float* __restrict__ outA,
                                               float* __restrict__ out) {
    __shared__ __align__(16) unsigned short AS[64 * BK2];    // 8 KB
    __shared__ __align__(16) unsigned short BS[128 * BK2];   // 16 KB
    const int t    = threadIdx.x;
    const int n0   = blockIdx.x * 128;          // grid.x = 4
    const int m0   = blockIdx.y * 64;           // grid.y = 64
    const int kz0  = blockIdx.z * (KCODES / 2); // ksplit 2
    float* dstC    = blockIdx.z ? out : outA;
    const int w    = t >> 6;
    const int lane = t & 63;
    const int wm   = (w >> 1) * 32;
    const int wn   = (w & 1) * 64;
    const int lrow = lane & 15;
    const int lq   = lane >> 4;
    const int srow = lane >> 3;        // staging row within 8-row chunk
    const int scol = (lane & 7) * 8;   // staging k-offset (shorts)

    const unsigned short* Asrc = enc16 + (size_t)(m0 + srow) * (2 * KCODES) + scol;
    const unsigned short* Bsrc = cbT   + (size_t)(n0 + srow) * KCODES + scol;

    f32x4 acc4[2][4];
    #pragma unroll
    for (int i = 0; i < 2; ++i)
        #pragma unroll
        for (int j = 0; j < 4; ++j)
            acc4[i][j] = (f32x4){0.f, 0.f, 0.f, 0.f};

    for (int kt = kz0; kt < kz0 + KCODES / 2; kt += BK2) {
        __syncthreads();
        #pragma unroll
        for (int j = 0; j < 2; ++j) {
            const int ja = w * 2 + j;
            cp16(Asrc + (size_t)(ja * 8) * (2 * KCODES) + kt, AS + ja * 512);
        }
        #pragma unroll
        for (int j = 0; j < 4; ++j) {
            const int jb = w * 4 + j;
            cp16(Bsrc + (size_t)(jb * 8) * KCODES + kt, BS + jb * 512);
        }
        __syncthreads();

        #pragma unroll
        for (int chunk = 0; chunk < 2; ++chunk) {
            short8 af[2];
            #pragma unroll
            for (int mt = 0; mt < 2; ++mt)
                af[mt] = *(const short8*)&AS[(wm + mt * 16 + lrow) * BK2 + chunk * 32 + lq * 8];
            #pragma unroll
            for (int nt = 0; nt < 4; ++nt) {
                const short8 bf = *(const short8*)&BS[(wn + nt * 16 + lrow) * BK2 + chunk * 32 + lq * 8];
                #pragma unroll
                for (int mt = 0; mt < 2; ++mt)
                    acc4[mt][nt] = __builtin_amdgcn_mfma_f32_16x16x32_bf16(af[mt], bf, acc4[mt][nt], 0, 0, 0);
            }
        }
    }

    #pragma unroll
    for (int mt = 0; mt < 2; ++mt)
        #pragma unroll
        for (int nt = 0; nt < 4; ++nt)
            #pragma unroll
            for (int r = 0; r < 4; ++r) {
                const int grow = m0 + wm + mt * 16 + lq * 4 + r;
                const int gcol = n0 + wn + nt * 16 + lrow;
                dstC[(size_t)grow * DDIM + gcol] = acc4[mt][nt][r];
            }
}

// ---------------- K5: tail (entropy + combine + cont. KLD + ticket) ---------
// blocks [0,32):   entropy from the ready colsum[8192] (32KB, L2-hot) — fast
// blocks [32,544): out = out + outA, accumulate (z-zhat)^2
// last of all 544 blocks (device ticket) finalizes loss + perplexity.
__global__ __launch_bounds__(256) void k_tail(const float* __restrict__ colsum,
                                              const float* __restrict__ z,
                                              const float* __restrict__ outA,
                                              const float* __restrict__ var_q,
                                              float* __restrict__ out,
                                              float* __restrict__ acc) {
    __shared__ float red[4];
    const int b = blockIdx.x;
    const int t = threadIdx.x;
    if (b < 32) {
        const float a = colsum[b * 256 + t] * INV_N;
        float ent = a * __logf(a + 1e-7f);
        ent = blockReduce1(ent, red);
        if (t == 0) atomicAdd(acc + 2, ent);
    } else {
        const size_t base = (size_t)(b - 32) * 4096 + t * 4;
        float p = 0.f;
        #pragma unroll
        for (int j = 0; j < 4; ++j) {
            const size_t idx = base + j * 1024;
            float4 o1 = *(const float4*)(out + idx);
            float4 o2 = *(const float4*)(outA + idx);
            float4 zv = *(const float4*)(z + idx);
            float4 s4;
            s4.x = o1.x + o2.x; s4.y = o1.y + o2.y;
            s4.z = o1.z + o2.z; s4.w = o1.w + o2.w;
            *(float4*)(out + idx) = s4;
            float dx = zv.x - s4.x, dy = zv.y - s4.y;
            float dz = zv.z - s4.z, dw = zv.w - s4.w;
            p += dx*dx + dy*dy + dz*dz + dw*dw;
        }
        p = blockReduce1(p, red);
        if (t == 0) atomicAdd(acc + 1, p);
    }
    // ticket: last of ALL 544 blocks finalizes (entropy + loss complete)
    if (t == 0) {
        __threadfence();
        unsigned* cnt = (unsigned*)(acc + 3);
        if (atomicAdd(cnt, 1u) == 543u) {
            float a0 = atomicAdd(acc + 0, 0.f);
            float a1 = atomicAdd(acc + 1, 0.f);
            float a2 = atomicAdd(acc + 2, 0.f);
            float wq = 0.5f / fmaxf(var_q[0], 1e-10f);
            out[(size_t)N_ROWS * DDIM]     = a0 / BS_F + a1 * wq / BS_F;
            out[(size_t)N_ROWS * DDIM + 1] = expf(-a2);
        }
    }
}

// ---------------- launch ----------------
extern "C" void kernel_launch(void* const* d_in, const int* in_sizes, int n_in,
                              void* d_out, int out_size, void* d_ws, size_t ws_size,
                              hipStream_t stream) {
    const float* z     = (const float*)d_in[0];
    const float* var_q = (const float*)d_in[1];
    const float* cb    = (const float*)d_in[2];
    float* out = (float*)d_out;
    float* ws  = (float*)d_ws;
    if (ws_size < (size_t)WS_FLOATS * sizeof(float)) return;  // need ~168 MB

    float* logit  = ws + OFF_LOGIT;
    float* cnorm  = ws + OFF_CNORM;
    float* accp   = ws + OFF_ACC;
    float* colsum = ws + OFF_COLSUM;
    unsigned short* zh  = (unsigned short*)(ws + OFF_ZH);
    unsigned short* zl  = (unsigned short*)(ws + OFF_ZL);
    unsigned short* cbh = (unsigned short*)(ws + OFF_CBH);
    unsigned short* cbl = (unsigned short*)(ws + OFF_CBL);
    unsigned short* cbT = (unsigned short*)(ws + OFF_CBT);
    float* outA = ws + OFF_CBL;   // cbl reused after gemm1 (8MB = 4096*512*4B)

    k_prep  <<<4097, 256, 0, stream>>>(z, cb, zh, zl, cbh, cbl, cbT, cnorm, accp, colsum);
    k_gemm1 <<<dim3(KCODES / 128, N_ROWS / 128), 256, 0, stream>>>(zh, zl, cbh, cbl, cnorm, var_q, logit);
    k_fused <<<1024, 256, 0, stream>>>(logit, colsum, accp);
    k_gemm2 <<<dim3(DDIM / 128, N_ROWS / 64, 2), 256, 0, stream>>>((const unsigned short*)logit, cbT, outA, out);
    k_tail  <<<544, 256, 0, stream>>>(colsum, z, outA, var_q, out, accp);
}

// Round 13
// 403.102 us; speedup vs baseline: 1.2636x; 1.2212x over previous
//
#include <hip/hip_runtime.h>
#include <stdint.h>

// ---------------- problem constants ----------------
#define N_ROWS 4096      // bs*seq = 8*512
#define DDIM   512
#define KCODES 8192
#define NK     (N_ROWS * KCODES)   // 33,554,432
#define HALF_NK 16777216u
#define BS_F   8.0f
#define INV_N  (1.0f / 4096.0f)

// ---------------- ws layout (float offsets) ----------------
// logit region (NK floats): after k_fused,
//  - row n's bf16 encodings live in the FIRST 16KB of row n's 32KB slot
//  - the UPPER 16KB halves of slots {4b, 4b+1 : b<512} hold k_fused block b's
//    colsum partial set (8192 floats) — written by the block that owns those
//    rows, AFTER it finishes reading them (no race).
// cbl (8MB) is DEAD after k_gemm1 -> reused as outA (gemm2 k-split partial 0).
#define OFF_LOGIT   0
#define OFF_CNORM   (NK)
#define OFF_ACC     (OFF_CNORM + KCODES)   // [0]=sum p*logp [1]=sum(z-zhat)^2 [2]=entropy [3]=ticket
#define OFF_ZH      (OFF_ACC + 4)                    // bf16 z hi  [4096*512]
#define OFF_ZL      (OFF_ZH + (N_ROWS*DDIM/2))       // bf16 z lo
#define OFF_CBH     (OFF_ZL + (N_ROWS*DDIM/2))       // bf16 cb hi [8192*512]
#define OFF_CBL     (OFF_CBH + (KCODES*DDIM/2))      // bf16 cb lo
#define OFF_CBT     (OFF_CBL + (KCODES*DDIM/2))      // bf16 cb^T  [512*8192]
#define WS_FLOATS   (OFF_CBT + (DDIM*KCODES/2))      // ~168MB

typedef __attribute__((ext_vector_type(8))) short short8;
typedef __attribute__((ext_vector_type(4))) float f32x4;

__device__ __forceinline__ unsigned short f2bf(float x) {
    uint32_t u = __float_as_uint(x);
    u += 0x7fffu + ((u >> 16) & 1u);
    return (unsigned short)(u >> 16);
}

// async global->LDS, 16B per lane; lds base wave-uniform, lane i -> +i*16.
__device__ __forceinline__ void cp16(const unsigned short* g, unsigned short* l) {
    __builtin_amdgcn_global_load_lds(
        (const __attribute__((address_space(1))) void*)g,
        (__attribute__((address_space(3))) void*)l, 16, 0, 0);
}

// ---------------- JAX threefry2x32-20, key(42) = (0,42) ----------------
__device__ __forceinline__ uint32_t rotl32(uint32_t x, int r) {
    return (x << r) | (x >> (32 - r));
}

__device__ __forceinline__ void threefry2(uint32_t c0, uint32_t c1,
                                          uint32_t& o0, uint32_t& o1) {
    const uint32_t ks0 = 0u, ks1 = 42u, ks2 = 0x1BD11BDAu ^ 0u ^ 42u;
    uint32_t x0 = c0 + ks0;
    uint32_t x1 = c1 + ks1;
#define TF_R(r) { x0 += x1; x1 = rotl32(x1, r); x1 ^= x0; }
    TF_R(13) TF_R(15) TF_R(26) TF_R(6)
    x0 += ks1; x1 += ks2 + 1u;
    TF_R(17) TF_R(29) TF_R(16) TF_R(24)
    x0 += ks2; x1 += ks0 + 2u;
    TF_R(13) TF_R(15) TF_R(26) TF_R(6)
    x0 += ks0; x1 += ks1 + 3u;
    TF_R(17) TF_R(29) TF_R(16) TF_R(24)
    x0 += ks1; x1 += ks2 + 4u;
    TF_R(13) TF_R(15) TF_R(26) TF_R(6)
    x0 += ks2; x1 += ks0 + 5u;
#undef TF_R
    o0 = x0; o1 = x1;
}

__device__ __forceinline__ float u01(uint32_t bits) {
    return __uint_as_float((bits >> 9) | 0x3f800000u) - 1.0f;
}

__device__ __forceinline__ float gum(uint32_t bits) {
    float u = u01(bits);
    return -__logf(-__logf(u + 1e-10f) + 1e-10f);
}

// ---------------- block reduce helpers (256 threads = 4 waves) ----------------
__device__ __forceinline__ float blockReduce1(float v, float* red) {
    #pragma unroll
    for (int o = 32; o > 0; o >>= 1) v += __shfl_down(v, o);
    __syncthreads();
    if ((threadIdx.x & 63) == 0) red[threadIdx.x >> 6] = v;
    __syncthreads();
    return red[0] + red[1] + red[2] + red[3];
}

__device__ __forceinline__ void red2max(float& a, float& b, float* red) {
    #pragma unroll
    for (int o = 32; o > 0; o >>= 1) {
        a = fmaxf(a, __shfl_down(a, o));
        b = fmaxf(b, __shfl_down(b, o));
    }
    __syncthreads();
    if ((threadIdx.x & 63) == 0) {
        red[(threadIdx.x >> 6) * 2 + 0] = a;
        red[(threadIdx.x >> 6) * 2 + 1] = b;
    }
    __syncthreads();
    a = fmaxf(fmaxf(red[0], red[2]), fmaxf(red[4], red[6]));
    b = fmaxf(fmaxf(red[1], red[3]), fmaxf(red[5], red[7]));
}

__device__ __forceinline__ void red3sum(float& a, float& b, float& c, float* red) {
    #pragma unroll
    for (int o = 32; o > 0; o >>= 1) {
        a += __shfl_down(a, o);
        b += __shfl_down(b, o);
        c += __shfl_down(c, o);
    }
    __syncthreads();
    if ((threadIdx.x & 63) == 0) {
        red[(threadIdx.x >> 6) * 3 + 0] = a;
        red[(threadIdx.x >> 6) * 3 + 1] = b;
        red[(threadIdx.x >> 6) * 3 + 2] = c;
    }
    __syncthreads();
    a = red[0] + red[3] + red[6] + red[9];
    b = red[1] + red[4] + red[7] + red[10];
    c = red[2] + red[5] + red[8] + red[11];
}

// ---------------- K1: fused prep ----------------
// blocks [0,1024):    split z  -> zh/zl
// blocks [1024,3072): split cb -> cbh/cbl + cnorm (wave = one cb row)
// blocks [3072,4096): transpose cb -> cbT bf16
// block  4096:        zero accp (incl. ticket counter)
__global__ __launch_bounds__(256) void k_prep(const float* __restrict__ z,
                                              const float* __restrict__ cb,
                                              unsigned short* __restrict__ zh,
                                              unsigned short* __restrict__ zl,
                                              unsigned short* __restrict__ cbh,
                                              unsigned short* __restrict__ cbl,
                                              unsigned short* __restrict__ cbT,
                                              float* __restrict__ cnorm,
                                              float* __restrict__ accp) {
    __shared__ unsigned short TT[64][65];
    const int b = blockIdx.x;
    const int t = threadIdx.x;
    if (b < 3072) {
        const bool isz = (b < 1024);
        const int bb = isz ? b : b - 1024;
        const float* src = isz ? z : cb;
        unsigned short* hi = isz ? zh : cbh;
        unsigned short* lo = isz ? zl : cbl;
        const size_t idx = ((size_t)bb * 256 + t) * 8;
        float4 a = *(const float4*)(src + idx);
        float4 bv = *(const float4*)(src + idx + 4);
        float f[8] = {a.x, a.y, a.z, a.w, bv.x, bv.y, bv.z, bv.w};
        unsigned short h8[8], l8[8];
        float s = 0.f;
        #pragma unroll
        for (int e = 0; e < 8; ++e) {
            unsigned short h = f2bf(f[e]);
            float hf = __uint_as_float((uint32_t)h << 16);
            h8[e] = h;
            l8[e] = f2bf(f[e] - hf);
            s += f[e] * f[e];
        }
        *(short8*)(hi + idx) = *(short8*)h8;
        *(short8*)(lo + idx) = *(short8*)l8;
        if (!isz) {
            #pragma unroll
            for (int o = 32; o > 0; o >>= 1) s += __shfl_down(s, o);
            if ((t & 63) == 0) cnorm[bb * 4 + (t >> 6)] = s;
        }
    } else if (b < 4096) {
        const int b3 = b - 3072;
        const int k0 = (b3 & 127) * 64;
        const int d0 = (b3 >> 7) * 64;
        #pragma unroll
        for (int j = 0; j < 4; ++j) {
            const int unit = t + j * 256;
            const int r = unit >> 4;
            const int s4 = unit & 15;
            float4 v = *(const float4*)(cb + (size_t)(k0 + r) * DDIM + d0 + s4 * 4);
            TT[r][s4*4+0] = f2bf(v.x); TT[r][s4*4+1] = f2bf(v.y);
            TT[r][s4*4+2] = f2bf(v.z); TT[r][s4*4+3] = f2bf(v.w);
        }
        __syncthreads();
        #pragma unroll
        for (int j = 0; j < 2; ++j) {
            const int unit = t + j * 256;
            const int dr = unit >> 3;
            const int ks = (unit & 7) * 8;
            unsigned short o8[8];
            #pragma unroll
            for (int i = 0; i < 8; ++i) o8[i] = TT[ks + i][dr];
            *(short8*)(cbT + (size_t)(d0 + dr) * KCODES + k0 + ks) = *(short8*)o8;
        }
    } else {
        if (t < 4) accp[t] = 0.f;
    }
}

// ---------------- K2: GEMM1 (MFMA, async LDS staging, bf16 3-term) ----------
// 128x128 tile, BK=32. At the 2-barrier-structure plateau (~31% MfmaUtil);
// pad (R4) and async staging (R5) measured neutral. Parked.
#define BK1 32
__global__ __launch_bounds__(256) void k_gemm1(const unsigned short* __restrict__ zh,
                                               const unsigned short* __restrict__ zl,
                                               const unsigned short* __restrict__ cbh,
                                               const unsigned short* __restrict__ cbl,
                                               const float* __restrict__ cnorm,
                                               const float* __restrict__ var_q,
                                               float* __restrict__ logit) {
    __shared__ __align__(16) unsigned short AH[128 * BK1];
    __shared__ __align__(16) unsigned short AL[128 * BK1];
    __shared__ __align__(16) unsigned short BH[128 * BK1];
    __shared__ __align__(16) unsigned short BL[128 * BK1];
    const int t    = threadIdx.x;
    const int n0   = blockIdx.x * 128;
    const int m0   = blockIdx.y * 128;
    const int w    = t >> 6;
    const int lane = t & 63;
    const int wm   = (w >> 1) * 64;
    const int wn   = (w & 1) * 64;
    const int lrow = lane & 15;
    const int lq   = lane >> 4;

    const unsigned short* src;
    unsigned short* dst;
    if      (w == 0) { src = zh;  dst = AH; }
    else if (w == 1) { src = zl;  dst = AL; }
    else if (w == 2) { src = cbh; dst = BH; }
    else             { src = cbl; dst = BL; }
    const int brow = (w < 2) ? m0 : n0;
    const unsigned short* gsrc = src + (size_t)(brow + (lane >> 2)) * DDIM + (lane & 3) * 8;

    f32x4 acc[4][4];
    #pragma unroll
    for (int i = 0; i < 4; ++i)
        #pragma unroll
        for (int j = 0; j < 4; ++j)
            acc[i][j] = (f32x4){0.f, 0.f, 0.f, 0.f};

    for (int kt = 0; kt < DDIM; kt += BK1) {
        __syncthreads();
        #pragma unroll
        for (int j = 0; j < 8; ++j)
            cp16(gsrc + (size_t)j * 16 * DDIM + kt, dst + j * 512);
        __syncthreads();

        short8 ah[4], al[4], bh[4], bl[4];
        #pragma unroll
        for (int mt = 0; mt < 4; ++mt) {
            const int row = wm + mt * 16 + lrow;
            ah[mt] = *(const short8*)&AH[row * BK1 + lq * 8];
            al[mt] = *(const short8*)&AL[row * BK1 + lq * 8];
        }
        #pragma unroll
        for (int nt = 0; nt < 4; ++nt) {
            const int row = wn + nt * 16 + lrow;
            bh[nt] = *(const short8*)&BH[row * BK1 + lq * 8];
            bl[nt] = *(const short8*)&BL[row * BK1 + lq * 8];
        }
        #pragma unroll
        for (int mt = 0; mt < 4; ++mt)
            #pragma unroll
            for (int nt = 0; nt < 4; ++nt) {
                acc[mt][nt] = __builtin_amdgcn_mfma_f32_16x16x32_bf16(ah[mt], bh[nt], acc[mt][nt], 0, 0, 0);
                acc[mt][nt] = __builtin_amdgcn_mfma_f32_16x16x32_bf16(ah[mt], bl[nt], acc[mt][nt], 0, 0, 0);
                acc[mt][nt] = __builtin_amdgcn_mfma_f32_16x16x32_bf16(al[mt], bh[nt], acc[mt][nt], 0, 0, 0);
            }
    }

    const float wq = 0.5f / fmaxf(var_q[0], 1e-10f);
    #pragma unroll
    for (int nt = 0; nt < 4; ++nt) {
        const int gcol = n0 + wn + nt * 16 + lrow;
        const float cn = cnorm[gcol];
        #pragma unroll
        for (int mt = 0; mt < 4; ++mt) {
            #pragma unroll
            for (int r = 0; r < 4; ++r) {
                const int grow = m0 + wm + mt * 16 + lq * 4 + r;
                logit[(size_t)grow * KCODES + gcol] = wq * (2.0f * acc[mt][nt][r] - cn);
            }
        }
    }
}

// ---------------- K3: fused stats + colsum + encodings ----------------
// 512 blocks, 4 row-pairs each (rows r=4b+i and r+2048, i=0..3).  One threefry
// per column serves both rows.  Colsum partial set b (8192 floats) spills to
// the upper 16KB halves of logit slots 4b, 4b+1 — self-owned rows, written
// after processing.  NO shared-state atomics (R12: 8.4M cross-XCD atomic RMWs
// = +130MB fabric writes, kernel 193us).
#define PROCESS_ROW(rr, garr)                                               \
  {                                                                         \
    const int rowi = (rr);                                                  \
    const float* lrowp = logit + (size_t)rowi * KCODES;                     \
    float l[32];                                                            \
    _Pragma("unroll")                                                       \
    for (int j = 0; j < 8; ++j) {                                           \
        float4 v = *(const float4*)(lrowp + t * 4 + j * 1024);              \
        l[j*4+0] = v.x; l[j*4+1] = v.y; l[j*4+2] = v.z; l[j*4+3] = v.w;     \
    }                                                                       \
    float m1 = -3.0e38f, m2 = -3.0e38f;                                     \
    _Pragma("unroll")                                                       \
    for (int e = 0; e < 32; ++e) {                                          \
        m1 = fmaxf(m1, l[e]);                                               \
        m2 = fmaxf(m2, (l[e] + garr[e]) * 2.0f);                            \
    }                                                                       \
    red2max(m1, m2, red);                                                   \
    float s1 = 0.f, t1 = 0.f, s2 = 0.f;                                     \
    _Pragma("unroll")                                                       \
    for (int e = 0; e < 32; ++e) {                                          \
        float x  = l[e] - m1;                                               \
        float y  = (l[e] + garr[e]) * 2.0f - m2;                            \
        float e1 = __expf(x);                                               \
        float e2 = __expf(y);                                               \
        s1 += e1; t1 += e1 * x; s2 += e2;                                   \
        l[e] = e1; garr[e] = e2;                                            \
    }                                                                       \
    red3sum(s1, t1, s2, red);                                               \
    const float is1 = 1.0f / s1, is2 = 1.0f / s2;                           \
    unsigned short o16[32];                                                 \
    _Pragma("unroll")                                                       \
    for (int e = 0; e < 32; ++e) {                                          \
        csum[e] += l[e] * is1;                                              \
        o16[e] = f2bf(garr[e] * is2);                                       \
    }                                                                       \
    unsigned short* dstp = (unsigned short*)logit + (size_t)rowi * (2 * KCODES); \
    _Pragma("unroll")                                                       \
    for (int j = 0; j < 8; ++j)                                             \
        *(ushort4*)(dstp + t * 4 + j * 1024) = *(ushort4*)&o16[j * 4];      \
    if (t == 0) kld += t1 * is1 - __logf(s1);                               \
  }

__global__ __launch_bounds__(256) void k_fused(float* __restrict__ logit,
                                               float* __restrict__ acc) {
    __shared__ float red[12];
    __shared__ float ghi[KCODES];   // pending gumbels for row r+2048
    const int b = blockIdx.x;       // 0..511
    const int t = threadIdx.x;
    float csum[32];
    #pragma unroll
    for (int e = 0; e < 32; ++e) csum[e] = 0.f;
    float kld = 0.f;

    for (int i = 0; i < 4; ++i) {
        const int r_lo = b * 4 + i;       // < 2048
        const int r_hi = r_lo + 2048;

        float g_lo[32];
        #pragma unroll
        for (int j = 0; j < 8; ++j)
            #pragma unroll
            for (int e4 = 0; e4 < 4; ++e4) {
                const uint32_t col = (uint32_t)(t * 4 + j * 1024 + e4);
                const uint32_t jg  = (uint32_t)r_lo * (uint32_t)KCODES + col;
                uint32_t b0, b1;
                threefry2(jg, jg + HALF_NK, b0, b1);
                g_lo[j*4+e4] = gum(b0);
                ghi[col] = gum(b1);       // thread-private slot, no barrier needed
            }

        PROCESS_ROW(r_lo, g_lo)

        float g_hi[32];
        #pragma unroll
        for (int j = 0; j < 8; ++j)
            #pragma unroll
            for (int e4 = 0; e4 < 4; ++e4)
                g_hi[j*4+e4] = ghi[t * 4 + j * 1024 + e4];

        PROCESS_ROW(r_hi, g_hi)
    }

    // spill colsum partial set b: col c -> slot (4b + c/4096), off 4096 + c%4096
    #pragma unroll
    for (int j = 0; j < 8; ++j) {
        const int c = t * 4 + j * 1024;
        float* dstp = logit + (size_t)(4 * b + (c >> 12)) * KCODES + 4096 + (c & 4095);
        *(float4*)dstp = make_float4(csum[j*4], csum[j*4+1], csum[j*4+2], csum[j*4+3]);
    }
    if (t == 0) atomicAdd(acc + 0, kld);
}

// ---------------- K4: GEMM2 z_hat = enc16 @ cbT^T (R8-proven shape, pure) ---
// 256 thr (4 waves 2x2), 64x128 tile, BK=64, ksplit=2 -> 512 blocks = 2/CU.
// z=0 -> outA partial, z=1 -> out partial (no atomics, no memset).
// NO serial epilogue (R10 straggler lesson).
#define BK2 64
__global__ __launch_bounds__(256) void k_gemm2(const unsigned short* __restrict__ enc16,
                                               const unsigned short* __restrict__ cbT,
                                               float* __restrict__ outA,
                                               float* __restrict__ out) {
    __shared__ __align__(16) unsigned short AS[64 * BK2];    // 8 KB
    __shared__ __align__(16) unsigned short BS[128 * BK2];   // 16 KB
    const int t    = threadIdx.x;
    const int n0   = blockIdx.x * 128;          // grid.x = 4
    const int m0   = blockIdx.y * 64;           // grid.y = 64
    const int kz0  = blockIdx.z * (KCODES / 2); // ksplit 2
    float* dstC    = blockIdx.z ? out : outA;
    const int w    = t >> 6;
    const int lane = t & 63;
    const int wm   = (w >> 1) * 32;
    const int wn   = (w & 1) * 64;
    const int lrow = lane & 15;
    const int lq   = lane >> 4;
    const int srow = lane >> 3;        // staging row within 8-row chunk
    const int scol = (lane & 7) * 8;   // staging k-offset (shorts)

    const unsigned short* Asrc = enc16 + (size_t)(m0 + srow) * (2 * KCODES) + scol;
    const unsigned short* Bsrc = cbT   + (size_t)(n0 + srow) * KCODES + scol;

    f32x4 acc4[2][4];
    #pragma unroll
    for (int i = 0; i < 2; ++i)
        #pragma unroll
        for (int j = 0; j < 4; ++j)
            acc4[i][j] = (f32x4){0.f, 0.f, 0.f, 0.f};

    for (int kt = kz0; kt < kz0 + KCODES / 2; kt += BK2) {
        __syncthreads();
        #pragma unroll
        for (int j = 0; j < 2; ++j) {
            const int ja = w * 2 + j;
            cp16(Asrc + (size_t)(ja * 8) * (2 * KCODES) + kt, AS + ja * 512);
        }
        #pragma unroll
        for (int j = 0; j < 4; ++j) {
            const int jb = w * 4 + j;
            cp16(Bsrc + (size_t)(jb * 8) * KCODES + kt, BS + jb * 512);
        }
        __syncthreads();

        #pragma unroll
        for (int chunk = 0; chunk < 2; ++chunk) {
            short8 af[2];
            #pragma unroll
            for (int mt = 0; mt < 2; ++mt)
                af[mt] = *(const short8*)&AS[(wm + mt * 16 + lrow) * BK2 + chunk * 32 + lq * 8];
            #pragma unroll
            for (int nt = 0; nt < 4; ++nt) {
                const short8 bf = *(const short8*)&BS[(wn + nt * 16 + lrow) * BK2 + chunk * 32 + lq * 8];
                #pragma unroll
                for (int mt = 0; mt < 2; ++mt)
                    acc4[mt][nt] = __builtin_amdgcn_mfma_f32_16x16x32_bf16(af[mt], bf, acc4[mt][nt], 0, 0, 0);
            }
        }
    }

    #pragma unroll
    for (int mt = 0; mt < 2; ++mt)
        #pragma unroll
        for (int nt = 0; nt < 4; ++nt)
            #pragma unroll
            for (int r = 0; r < 4; ++r) {
                const int grow = m0 + wm + mt * 16 + lq * 4 + r;
                const int gcol = n0 + wn + nt * 16 + lrow;
                dstC[(size_t)grow * DDIM + gcol] = acc4[mt][nt][r];
            }
}

// ---------------- K5: tail (combine + loss2 | owned-column entropy | ticket) -
// blocks [0,512):   out = out + outA, accumulate (z-zhat)^2
// blocks [512,768): reduce+entropy — block rb-512 OWNS 32 columns: sums them
//                   over all 512 partial sets (written by k_fused, coherent at
//                   dispatch boundary), computes their entropy contribution
//                   locally, one scalar atomicAdd.  256-way parallel — no
//                   straggler (R11 lesson), no shared colsum (R12 lesson).
// last of all 768 blocks (device ticket) finalizes loss + perplexity.
__global__ __launch_bounds__(256) void k_tail(const float* __restrict__ logit,
                                              const float* __restrict__ z,
                                              const float* __restrict__ outA,
                                              const float* __restrict__ var_q,
                                              float* __restrict__ out,
                                              float* __restrict__ acc) {
    __shared__ float red[4];
    __shared__ float cred[8][32];
    const int b = blockIdx.x;
    const int t = threadIdx.x;
    if (b < 512) {
        const size_t base = (size_t)b * 4096 + t * 4;
        float p = 0.f;
        #pragma unroll
        for (int j = 0; j < 4; ++j) {
            const size_t idx = base + j * 1024;
            float4 o1 = *(const float4*)(out + idx);
            float4 o2 = *(const float4*)(outA + idx);
            float4 zv = *(const float4*)(z + idx);
            float4 s4;
            s4.x = o1.x + o2.x; s4.y = o1.y + o2.y;
            s4.z = o1.z + o2.z; s4.w = o1.w + o2.w;
            *(float4*)(out + idx) = s4;
            float dx = zv.x - s4.x, dy = zv.y - s4.y;
            float dz = zv.z - s4.z, dw = zv.w - s4.w;
            p += dx*dx + dy*dy + dz*dz + dw*dw;
        }
        p = blockReduce1(p, red);
        if (t == 0) atomicAdd(acc + 1, p);
    } else {
        const int rb  = b - 512;          // 0..255
        const int cl  = t & 31;           // column within block's range
        const int ch  = t >> 5;           // chunk 0..7 (64 sets each)
        const int col = rb * 32 + cl;
        const size_t off = (size_t)(col >> 12) * KCODES + 4096 + (col & 4095);
        float s = 0.f;
        for (int s2 = 0; s2 < 64; ++s2) {
            const int set = ch * 64 + s2;
            s += logit[(size_t)(4 * set) * KCODES + off];
        }
        cred[ch][cl] = s;
        __syncthreads();
        float ent = 0.f;
        if (t < 32) {
            float tot = 0.f;
            #pragma unroll
            for (int c2 = 0; c2 < 8; ++c2) tot += cred[c2][t];
            float a = tot * INV_N;
            ent = a * __logf(a + 1e-7f);
            #pragma unroll
            for (int o = 16; o > 0; o >>= 1) ent += __shfl_down(ent, o);
            if (t == 0) atomicAdd(acc + 2, ent);
        }
    }
    // ticket: last of ALL 768 blocks finalizes (entropy + loss complete)
    if (t == 0) {
        __threadfence();
        unsigned* cnt = (unsigned*)(acc + 3);
        if (atomicAdd(cnt, 1u) == 767u) {
            float a0 = atomicAdd(acc + 0, 0.f);
            float a1 = atomicAdd(acc + 1, 0.f);
            float a2 = atomicAdd(acc + 2, 0.f);
            float wq = 0.5f / fmaxf(var_q[0], 1e-10f);
            out[(size_t)N_ROWS * DDIM]     = a0 / BS_F + a1 * wq / BS_F;
            out[(size_t)N_ROWS * DDIM + 1] = expf(-a2);
        }
    }
}

// ---------------- launch ----------------
extern "C" void kernel_launch(void* const* d_in, const int* in_sizes, int n_in,
                              void* d_out, int out_size, void* d_ws, size_t ws_size,
                              hipStream_t stream) {
    const float* z     = (const float*)d_in[0];
    const float* var_q = (const float*)d_in[1];
    const float* cb    = (const float*)d_in[2];
    float* out = (float*)d_out;
    float* ws  = (float*)d_ws;
    if (ws_size < (size_t)WS_FLOATS * sizeof(float)) return;  // need ~168 MB

    float* logit  = ws + OFF_LOGIT;
    float* cnorm  = ws + OFF_CNORM;
    float* accp   = ws + OFF_ACC;
    unsigned short* zh  = (unsigned short*)(ws + OFF_ZH);
    unsigned short* zl  = (unsigned short*)(ws + OFF_ZL);
    unsigned short* cbh = (unsigned short*)(ws + OFF_CBH);
    unsigned short* cbl = (unsigned short*)(ws + OFF_CBL);
    unsigned short* cbT = (unsigned short*)(ws + OFF_CBT);
    float* outA = ws + OFF_CBL;   // cbl reused after gemm1 (8MB = 4096*512*4B)

    k_prep  <<<4097, 256, 0, stream>>>(z, cb, zh, zl, cbh, cbl, cbT, cnorm, accp);
    k_gemm1 <<<dim3(KCODES / 128, N_ROWS / 128), 256, 0, stream>>>(zh, zl, cbh, cbl, cnorm, var_q, logit);
    k_fused <<<512, 256, 0, stream>>>(logit, accp);
    k_gemm2 <<<dim3(DDIM / 128, N_ROWS / 64, 2), 256, 0, stream>>>((const unsigned short*)logit, cbT, outA, out);
    k_tail  <<<768, 256, 0, stream>>>(logit, z, outA, var_q, out, accp);
}